// Round 9
// baseline (86.680 us; speedup 1.0000x reference)
//
#include <hip/hip_runtime.h>

// ---------------------------------------------------------------------------
// Patcher: 8 images (1024x1024x3 f32), 8 boxes each (64x64), per box:
//   crop -> bilinear up 128 -> conv3x3 SAME + tanh -> loss += mean((im-pb)^2)
//   -> bilinear down 64 -> scatter -> (clip is a no-op for these inputs)
// Output: patched images (25165824 f32) ++ cumsum of per-image losses (8 f32).
//
// Round 9: phase-separated copy. Evidence so far: THREE copy implementations
// (grid-stride kernel, contiguous+nt kernel, runtime D2D blit) all ~57-63us
// (~2.4-3.5 TB/s combined), while the harness's pure-write fill on the SAME
// d_out runs 7 TB/s. Counters: gin only half L3-resident (FETCH=49MB every
// replay), gout written through (WRITE=98MB every replay). Theory: 200MB
// read+write working set thrashes the 256MB MALL when interleaved.
// Fix: time-separate the streams --
//   1. warm_kernel: pure-read pass over gin (asm keep-alive), makes gin
//      fully L3-resident; also zeroes the 64 box flags (replaces init node)
//   2. copy_kernel: reads gin (L3 hits), nontemporal stores to gout
//      (write stream doesn't evict gin)
//   3. patch_kernel (r5 band-split, unchanged)
//   4. finalize (unchanged)
// ---------------------------------------------------------------------------

#define PTHR 256
#define NPB 512  // 64 boxes x 8 bands

#define IMG_FLOATS (1024 * 1024 * 3)        // 3145728
#define COPY_BLOCKS 2048
#define COPY_THREADS 256
#define LOSS_OFF ((size_t)IMG_FLOATS * 8)   // 25165824

typedef float f32x4 __attribute__((ext_vector_type(4)));

__device__ __forceinline__ int iclamp(int v, int lo, int hi) {
  return v < lo ? lo : (v > hi ? hi : v);
}
__device__ __forceinline__ float tanh_fast(float x) {
  float t = __expf(2.0f * x);
  return 1.0f - 2.0f / (t + 1.0f);  // inf-safe tanh
}

// ---------------- kernel 0: warm gin into L3 + zero flags ------------------
__global__ __launch_bounds__(COPY_THREADS) void warm_kernel(
    const f32x4* __restrict__ gin, int* __restrict__ wsI) {
  if (blockIdx.x == 0 && threadIdx.x < 128) wsI[threadIdx.x] = 0;
  const size_t base = (size_t)blockIdx.x * 3072 + threadIdx.x;
  f32x4 acc = {0.f, 0.f, 0.f, 0.f};
#pragma unroll
  for (int q = 0; q < 12; ++q) acc += gin[base + (size_t)q * COPY_THREADS];
  // keep the loads live without any store traffic (rule: ablation-via-skip
  // DCEs upstream ops -- asm keep-alive instead)
  asm volatile("" ::"v"(acc.x), "v"(acc.y), "v"(acc.z), "v"(acc.w));
}

// ------------------------- kernel 1: copy ----------------------------------
// 6291456 float4 chunks = 2048 blocks x 3072 chunks (contiguous per block).
// Reads should hit L3 (warmed); stores nontemporal so they don't evict gin.
__global__ __launch_bounds__(COPY_THREADS) void copy_kernel(
    const f32x4* __restrict__ gin, f32x4* __restrict__ gout) {
  const size_t base = (size_t)blockIdx.x * 3072 + threadIdx.x;
  f32x4 v[12];
#pragma unroll
  for (int q = 0; q < 12; ++q) v[q] = gin[base + (size_t)q * COPY_THREADS];
#pragma unroll
  for (int q = 0; q < 12; ++q)
    __builtin_nontemporal_store(v[q], &gout[base + (size_t)q * COPY_THREADS]);
}

// ------------------------- kernel 2: patch bands ---------------------------
__global__ __launch_bounds__(PTHR, 2) void patch_kernel(
    const float* __restrict__ gin, const float* __restrict__ gW,
    const int* __restrict__ gbox, float* __restrict__ gout,
    int* __restrict__ wsI, float* __restrict__ wsLoss) {
  __shared__ float sCrop[12][193];   // 9264 B: crop rows [8b-2, 8b+9] clamped
  __shared__ float sPlane[18][129];  // 9288 B: plane rows [16b-1, 16b+16]
  __shared__ float sWred[4];

  const int bid = blockIdx.x;
  const int tid = threadIdx.x;
  const int box = bid >> 3;   // 0..63
  const int band = bid & 7;   // 0..7
  const int img = box >> 3;
  const int k = box & 7;
  int* boxDone = wsI;  // [64] per-box completed-band counters

  int jy[8], jx[8];
#pragma unroll
  for (int j = 0; j < 8; ++j) {
    jy[j] = gbox[img * 16 + 2 * j];
    jx[j] = gbox[img * 16 + 2 * j + 1];
  }
  int y0 = 0, x0 = 0;
#pragma unroll
  for (int j = 0; j < 8; ++j)
    if (j == k) { y0 = jy[j]; x0 = jx[j]; }

  bool ov[8];
  bool hasPred = false, hasSucc = false;
#pragma unroll
  for (int j = 0; j < 8; ++j) {
    int dy = y0 - jy[j]; dy = dy < 0 ? -dy : dy;
    int dx = x0 - jx[j]; dx = dx < 0 ? -dx : dx;
    ov[j] = (dy < 64) && (dx < 64);
    hasPred = hasPred || (j < k && ov[j]);
    hasSucc = hasSucc || (j > k && ov[j]);
  }

  // ---- wait for overlapping predecessor boxes (all 8 bands done; RARE) ----
  if (tid == 0 && hasPred) {
#pragma unroll
    for (int j = 0; j < 8; ++j) {
      if (j < k && ov[j]) {
        while (__hip_atomic_load(&boxDone[img * 8 + j], __ATOMIC_RELAXED,
                                 __HIP_MEMORY_SCOPE_AGENT) < 8) {
          __builtin_amdgcn_s_sleep(2);
        }
      }
    }
    __builtin_amdgcn_fence(__ATOMIC_ACQUIRE, "agent");
  }
  __syncthreads();

  const size_t ibase = (size_t)img * IMG_FLOATS;
  const int cropBase = 8 * band - 2;  // global crop row of sCrop[0]

  // ---- stage 1: crop rows -> LDS (12 rows x 64 px x 3ch = 768 px) ----
#pragma unroll
  for (int q = 0; q < 3; ++q) {
    const int idx = tid + q * PTHR;
    const int r = idx >> 6, col = idx & 63;
    const int gr = iclamp(cropBase + r, 0, 63);
    const int gy = y0 + gr, gx = x0 + col;
    const float* src = gin;
    if (hasPred) {
      bool covered = false;
#pragma unroll
      for (int j = 0; j < 8; ++j) {
        bool cj = (j < k) && ((unsigned)(gy - jy[j]) < 64u) &&
                  ((unsigned)(gx - jx[j]) < 64u);
        covered = covered || cj;
      }
      if (covered) src = gout;
    }
    const size_t a = ibase + ((size_t)gy * 1024 + gx) * 3;
    sCrop[r][col * 3 + 0] = src[a + 0];
    sCrop[r][col * 3 + 1] = src[a + 1];
    sCrop[r][col * 3 + 2] = src[a + 2];
  }
  __syncthreads();

  // thread geometry: own tile = 4 plane rows x 2 cols
  const int m = tid >> 6, tx = tid & 63;
  const int r0 = 16 * band + 4 * m;  // global plane row base of my tile
  // halo: 1 plane px per thread (rows 16b-1 and 16b+16, clamped)
  const int hg = (tid < 128) ? 16 * band - 1 : 16 * band + 16;
  const int hh = iclamp(hg, 0, 127);
  const int hx = tid & 127;
  const int hslot = (tid < 128) ? 0 : 17;

  float lossAcc = 0.f;

#pragma unroll 1
  for (int c = 0; c < 3; ++c) {
    // hoist 27 conv weights into registers (static indexing below)
    float wk[27];
#pragma unroll
    for (int t9 = 0; t9 < 9; ++t9)
#pragma unroll
      for (int ci = 0; ci < 3; ++ci) wk[ci * 9 + t9] = gW[(t9 * 3 + ci) * 3 + c];

    float acc[4][2];
#pragma unroll
    for (int p = 0; p < 4; ++p) { acc[p][0] = 0.f; acc[p][1] = 0.f; }
    float pbown[4][2];

#pragma unroll
    for (int ci = 0; ci < 3; ++ci) {
      // crop neighborhood: rows (local) 2m+1..2m+4, cols tx-1..tx+1 clamped
      float cv[4][3];
#pragma unroll
      for (int a = 0; a < 4; ++a)
#pragma unroll
        for (int b = 0; b < 3; ++b)
          cv[a][b] = sCrop[2 * m + 1 + a][iclamp(tx - 1 + b, 0, 63) * 3 + ci];
      // horizontal upsample -> pb cols 2tx-1..2tx+2
      float tmp[4][4];
#pragma unroll
      for (int a = 0; a < 4; ++a) {
        tmp[a][0] = 0.75f * cv[a][0] + 0.25f * cv[a][1];
        tmp[a][1] = 0.25f * cv[a][0] + 0.75f * cv[a][1];
        tmp[a][2] = 0.75f * cv[a][1] + 0.25f * cv[a][2];
        tmp[a][3] = 0.25f * cv[a][1] + 0.75f * cv[a][2];
      }
      // vertical upsample, pb rows U = r0-1+i, streamed; conv accumulate
#pragma unroll
      for (int i = 0; i < 6; ++i) {
        float pr[4];
        const int a = i >> 1;
        const float w = (i & 1) ? 0.25f : 0.75f;
#pragma unroll
        for (int j = 0; j < 4; ++j)
          pr[j] = w * tmp[a][j] + (1.0f - w) * tmp[a + 1][j];
        // conv SAME zero padding at pb borders
        if (i == 0 && r0 == 0) { pr[0] = pr[1] = pr[2] = pr[3] = 0.f; }
        if (i == 5 && r0 == 124) { pr[0] = pr[1] = pr[2] = pr[3] = 0.f; }
        if (tx == 0) pr[0] = 0.f;
        if (tx == 63) pr[3] = 0.f;
        if (ci == c && i >= 1 && i <= 4) {
          pbown[i - 1][0] = pr[1];
          pbown[i - 1][1] = pr[2];
        }
#pragma unroll
        for (int p = 0; p < 4; ++p) {
          const int du = i - p;
          if (du >= 0 && du < 3) {
#pragma unroll
            for (int dv = 0; dv < 3; ++dv) {
              const float wt = wk[ci * 9 + du * 3 + dv];
              acc[p][0] += wt * pr[dv];
              acc[p][1] += wt * pr[1 + dv];
            }
          }
        }
      }
    }
    // tanh + loss + stage own plane rows (local rows 1..16)
#pragma unroll
    for (int p = 0; p < 4; ++p)
#pragma unroll
      for (int q = 0; q < 2; ++q) {
        const float imv = tanh_fast(acc[p][q]);
        const float d = imv - pbown[p][q];
        lossAcc += d * d;
        sPlane[4 * m + p + 1][2 * tx + q] = imv;
      }

    // halo plane px (recomputed; local rows 0 and 17)
    float hacc = 0.f;
#pragma unroll
    for (int ci = 0; ci < 3; ++ci) {
#pragma unroll
      for (int du = 0; du < 3; ++du) {
        const int U = hh - 1 + du;
        if (U >= 0 && U < 128) {
          const int Lr = (U - 1) >> 1;
          const float wr = (U & 1) ? 0.75f : 0.25f;
          const int l0 = Lr - cropBase, l1 = l0 + 1;
#pragma unroll
          for (int dv = 0; dv < 3; ++dv) {
            const int V = hx - 1 + dv;
            if (V >= 0 && V < 128) {
              const int Lc = (V - 1) >> 1;
              const float wc = (V & 1) ? 0.75f : 0.25f;
              const int c0 = iclamp(Lc, 0, 63) * 3 + ci;
              const int c1 = iclamp(Lc + 1, 0, 63) * 3 + ci;
              const float v0 = wc * sCrop[l0][c0] + (1.0f - wc) * sCrop[l0][c1];
              const float v1 = wc * sCrop[l1][c0] + (1.0f - wc) * sCrop[l1][c1];
              hacc += wk[ci * 9 + du * 3 + dv] * (wr * v0 + (1.0f - wr) * v1);
            }
          }
        }
      }
    }
    sPlane[hslot][hx] = tanh_fast(hacc);
    __syncthreads();

    // downsample 128->64 (4-tap antialiased) for my 8 output rows
    constexpr float W37 = 0.75f / 1.75f;
    constexpr float W17 = 0.25f / 1.75f;
    const int pbase = 16 * band - 1;  // global plane row of sPlane[0]
#pragma unroll
    for (int q2 = 0; q2 < 2; ++q2) {
      const int idx = tid + q2 * PTHR;
      const int Y = 8 * band + (idx >> 6), X = idx & 63;
      float wy[4] = {0.125f, 0.375f, 0.375f, 0.125f};
      float wx[4] = {0.125f, 0.375f, 0.375f, 0.125f};
      if (Y == 0) { wy[0] = 0.f; wy[1] = W37; wy[2] = W37; wy[3] = W17; }
      if (Y == 63) { wy[0] = W17; wy[1] = W37; wy[2] = W37; wy[3] = 0.f; }
      if (X == 0) { wx[0] = 0.f; wx[1] = W37; wx[2] = W37; wx[3] = W17; }
      if (X == 63) { wx[0] = W17; wx[1] = W37; wx[2] = W37; wx[3] = 0.f; }
      float sum = 0.f;
#pragma unroll
      for (int t2 = 0; t2 < 4; ++t2) {
        const int ryl = iclamp(2 * Y - 1 + t2, 0, 127) - pbase;
        float rs = 0.f;
#pragma unroll
        for (int u = 0; u < 4; ++u)
          rs += wx[u] * sPlane[ryl][iclamp(2 * X - 1 + u, 0, 127)];
        sum += wy[t2] * rs;
      }
      gout[ibase + ((size_t)(y0 + Y) * 1024 + (x0 + X)) * 3 + c] = sum;
    }
    __syncthreads();  // before sPlane reuse by next channel
  }

  // ---- band loss partial: block reduce (4 waves) -> ws[bid] ----
#pragma unroll
  for (int mm = 32; mm >= 1; mm >>= 1) lossAcc += __shfl_xor(lossAcc, mm, 64);
  if ((tid & 63) == 0) sWred[tid >> 6] = lossAcc;
  __syncthreads();
  if (tid == 0)
    wsLoss[bid] = sWred[0] + sWred[1] + sWred[2] + sWred[3];  // raw sum

  // ---- publish to overlapping successor boxes only (RARE) ----
  if (hasSucc) {
    __syncthreads();
    if (tid == 0) {
      __threadfence();
      __hip_atomic_fetch_add(&boxDone[img * 8 + k], 1, __ATOMIC_RELEASE,
                             __HIP_MEMORY_SCOPE_AGENT);
    }
  }
}

// ------------------------- kernel 3: loss cumsum ---------------------------
__global__ __launch_bounds__(64) void finalize_kernel(
    const float* __restrict__ wsLoss, float* __restrict__ gout) {
  __shared__ float simg[8];
  const int t = threadIdx.x;
  if (t < 8) {
    float s = 0.f;
    for (int i = 0; i < 64; ++i) s += wsLoss[t * 64 + i];  // fixed order
    simg[t] = s / 49152.0f;  // mean over 128*128*3, summed per image
  }
  __syncthreads();
  if (t == 0) {
    float run = 0.f;
#pragma unroll
    for (int im = 0; im < 8; ++im) {
      run += simg[im];
      gout[LOSS_OFF + im] = run;
    }
  }
}

extern "C" void kernel_launch(void* const* d_in, const int* in_sizes, int n_in,
                              void* d_out, int out_size, void* d_ws, size_t ws_size,
                              hipStream_t stream) {
  (void)in_sizes; (void)n_in; (void)out_size; (void)ws_size;
  const float* gin = (const float*)d_in[0];   // images (8,1024,1024,3) f32
  const float* gW = (const float*)d_in[1];    // W (3,3,3,3) f32, HWIO
  const int* gbox = (const int*)d_in[2];      // box_yx (8,8,2) i32
  float* gout = (float*)d_out;
  int* wsI = (int*)d_ws;                      // boxDone[64] at byte 0
  float* wsLoss = (float*)d_ws + 128;         // 512 floats at byte 512

  hipLaunchKernelGGL(warm_kernel, dim3(COPY_BLOCKS), dim3(COPY_THREADS), 0,
                     stream, (const f32x4*)gin, wsI);
  hipLaunchKernelGGL(copy_kernel, dim3(COPY_BLOCKS), dim3(COPY_THREADS), 0,
                     stream, (const f32x4*)gin, (f32x4*)gout);
  hipLaunchKernelGGL(patch_kernel, dim3(NPB), dim3(PTHR), 0, stream,
                     gin, gW, gbox, gout, wsI, wsLoss);
  hipLaunchKernelGGL(finalize_kernel, dim3(1), dim3(64), 0, stream,
                     wsLoss, gout);
}

// Round 10
// 86.508 us; speedup vs baseline: 1.0020x; 1.0020x over previous
//
#include <hip/hip_runtime.h>

// ---------------------------------------------------------------------------
// Patcher: 8 images (1024x1024x3 f32), 8 boxes each (64x64), per box:
//   crop -> bilinear up 128 -> conv3x3 SAME + tanh -> loss += mean((im-pb)^2)
//   -> bilinear down 64 -> scatter -> (clip is a no-op for these inputs)
// Output: patched images (25165824 f32) ++ cumsum of per-image losses (8 f32).
//
// Round 10: MEASUREMENT round for the 57us copy wall. Four implementations
// (grid-stride, contiguous+nt, D2D blit, warmed+nt) all ~57-63us (~2.5-3.5
// TB/s combined) while pure writes on this machine do 7 TB/s. Axes untested:
// (a) is d_out's write path itself slow? (b) do nt/cache flags matter at all?
// So: copy split into thirds, one variant each (per-dispatch rocprof rows):
//   probe_out: pure nt-write of zeros over third 0 (copy_a overwrites after;
//              final state correct) -> pure-write BW of d_out
//   copy_a: plain load / plain store   (third 0)
//   copy_b: plain load / nt store      (third 1)  == r7 config
//   copy_c: nt load  / nt store        (third 2)
// Patch (r5 band-split) and finalize unchanged. Warm kernel dropped (r9: -12us
// regression, null effect on copy).
// ---------------------------------------------------------------------------

#define PTHR 256
#define NPB 512  // 64 boxes x 8 bands

#define IMG_FLOATS (1024 * 1024 * 3)        // 3145728
#define COPY_BLOCKS 2048
#define COPY_THREADS 256
#define THIRD_CHUNKS ((size_t)2097152)      // 6291456 f32x4 chunks / 3
#define LOSS_OFF ((size_t)IMG_FLOATS * 8)   // 25165824

typedef float f32x4 __attribute__((ext_vector_type(4)));

__device__ __forceinline__ int iclamp(int v, int lo, int hi) {
  return v < lo ? lo : (v > hi ? hi : v);
}
__device__ __forceinline__ float tanh_fast(float x) {
  float t = __expf(2.0f * x);
  return 1.0f - 2.0f / (t + 1.0f);  // inf-safe tanh
}

// ------------------- kernel 0: zero the sync flags -------------------------
__global__ __launch_bounds__(128) void init_kernel(int* __restrict__ wsI) {
  wsI[threadIdx.x] = 0;
}

// ---- probe: pure nt-write of zeros to gout third 0 (overwritten later) ----
__global__ __launch_bounds__(COPY_THREADS) void probe_out(
    f32x4* __restrict__ gout) {
  const size_t base = (size_t)blockIdx.x * 1024 + threadIdx.x;
  const f32x4 z = {0.f, 0.f, 0.f, 0.f};
#pragma unroll
  for (int q = 0; q < 4; ++q)
    __builtin_nontemporal_store(z, &gout[base + (size_t)q * COPY_THREADS]);
}

// ---- copy variants: 2048 blocks x 1024 chunks (16KB contiguous/block) -----
__global__ __launch_bounds__(COPY_THREADS) void copy_a(  // plain / plain
    const f32x4* __restrict__ gin, f32x4* __restrict__ gout) {
  const size_t base = (size_t)blockIdx.x * 1024 + threadIdx.x;
  f32x4 v[4];
#pragma unroll
  for (int q = 0; q < 4; ++q) v[q] = gin[base + (size_t)q * COPY_THREADS];
#pragma unroll
  for (int q = 0; q < 4; ++q) gout[base + (size_t)q * COPY_THREADS] = v[q];
}

__global__ __launch_bounds__(COPY_THREADS) void copy_b(  // plain / nt
    const f32x4* __restrict__ gin, f32x4* __restrict__ gout) {
  const size_t base = THIRD_CHUNKS + (size_t)blockIdx.x * 1024 + threadIdx.x;
  f32x4 v[4];
#pragma unroll
  for (int q = 0; q < 4; ++q) v[q] = gin[base + (size_t)q * COPY_THREADS];
#pragma unroll
  for (int q = 0; q < 4; ++q)
    __builtin_nontemporal_store(v[q], &gout[base + (size_t)q * COPY_THREADS]);
}

__global__ __launch_bounds__(COPY_THREADS) void copy_c(  // nt / nt
    const f32x4* __restrict__ gin, f32x4* __restrict__ gout) {
  const size_t base =
      2 * THIRD_CHUNKS + (size_t)blockIdx.x * 1024 + threadIdx.x;
  f32x4 v[4];
#pragma unroll
  for (int q = 0; q < 4; ++q)
    v[q] = __builtin_nontemporal_load(&gin[base + (size_t)q * COPY_THREADS]);
#pragma unroll
  for (int q = 0; q < 4; ++q)
    __builtin_nontemporal_store(v[q], &gout[base + (size_t)q * COPY_THREADS]);
}

// ------------------------- kernel 2: patch bands ---------------------------
__global__ __launch_bounds__(PTHR, 2) void patch_kernel(
    const float* __restrict__ gin, const float* __restrict__ gW,
    const int* __restrict__ gbox, float* __restrict__ gout,
    int* __restrict__ wsI, float* __restrict__ wsLoss) {
  __shared__ float sCrop[12][193];   // 9264 B: crop rows [8b-2, 8b+9] clamped
  __shared__ float sPlane[18][129];  // 9288 B: plane rows [16b-1, 16b+16]
  __shared__ float sWred[4];

  const int bid = blockIdx.x;
  const int tid = threadIdx.x;
  const int box = bid >> 3;   // 0..63
  const int band = bid & 7;   // 0..7
  const int img = box >> 3;
  const int k = box & 7;
  int* boxDone = wsI;  // [64] per-box completed-band counters

  int jy[8], jx[8];
#pragma unroll
  for (int j = 0; j < 8; ++j) {
    jy[j] = gbox[img * 16 + 2 * j];
    jx[j] = gbox[img * 16 + 2 * j + 1];
  }
  int y0 = 0, x0 = 0;
#pragma unroll
  for (int j = 0; j < 8; ++j)
    if (j == k) { y0 = jy[j]; x0 = jx[j]; }

  bool ov[8];
  bool hasPred = false, hasSucc = false;
#pragma unroll
  for (int j = 0; j < 8; ++j) {
    int dy = y0 - jy[j]; dy = dy < 0 ? -dy : dy;
    int dx = x0 - jx[j]; dx = dx < 0 ? -dx : dx;
    ov[j] = (dy < 64) && (dx < 64);
    hasPred = hasPred || (j < k && ov[j]);
    hasSucc = hasSucc || (j > k && ov[j]);
  }

  // ---- wait for overlapping predecessor boxes (all 8 bands done; RARE) ----
  if (tid == 0 && hasPred) {
#pragma unroll
    for (int j = 0; j < 8; ++j) {
      if (j < k && ov[j]) {
        while (__hip_atomic_load(&boxDone[img * 8 + j], __ATOMIC_RELAXED,
                                 __HIP_MEMORY_SCOPE_AGENT) < 8) {
          __builtin_amdgcn_s_sleep(2);
        }
      }
    }
    __builtin_amdgcn_fence(__ATOMIC_ACQUIRE, "agent");
  }
  __syncthreads();

  const size_t ibase = (size_t)img * IMG_FLOATS;
  const int cropBase = 8 * band - 2;  // global crop row of sCrop[0]

  // ---- stage 1: crop rows -> LDS (12 rows x 64 px x 3ch = 768 px) ----
#pragma unroll
  for (int q = 0; q < 3; ++q) {
    const int idx = tid + q * PTHR;
    const int r = idx >> 6, col = idx & 63;
    const int gr = iclamp(cropBase + r, 0, 63);
    const int gy = y0 + gr, gx = x0 + col;
    const float* src = gin;
    if (hasPred) {
      bool covered = false;
#pragma unroll
      for (int j = 0; j < 8; ++j) {
        bool cj = (j < k) && ((unsigned)(gy - jy[j]) < 64u) &&
                  ((unsigned)(gx - jx[j]) < 64u);
        covered = covered || cj;
      }
      if (covered) src = gout;
    }
    const size_t a = ibase + ((size_t)gy * 1024 + gx) * 3;
    sCrop[r][col * 3 + 0] = src[a + 0];
    sCrop[r][col * 3 + 1] = src[a + 1];
    sCrop[r][col * 3 + 2] = src[a + 2];
  }
  __syncthreads();

  // thread geometry: own tile = 4 plane rows x 2 cols
  const int m = tid >> 6, tx = tid & 63;
  const int r0 = 16 * band + 4 * m;  // global plane row base of my tile
  // halo: 1 plane px per thread (rows 16b-1 and 16b+16, clamped)
  const int hg = (tid < 128) ? 16 * band - 1 : 16 * band + 16;
  const int hh = iclamp(hg, 0, 127);
  const int hx = tid & 127;
  const int hslot = (tid < 128) ? 0 : 17;

  float lossAcc = 0.f;

#pragma unroll 1
  for (int c = 0; c < 3; ++c) {
    // hoist 27 conv weights into registers (static indexing below)
    float wk[27];
#pragma unroll
    for (int t9 = 0; t9 < 9; ++t9)
#pragma unroll
      for (int ci = 0; ci < 3; ++ci) wk[ci * 9 + t9] = gW[(t9 * 3 + ci) * 3 + c];

    float acc[4][2];
#pragma unroll
    for (int p = 0; p < 4; ++p) { acc[p][0] = 0.f; acc[p][1] = 0.f; }
    float pbown[4][2];

#pragma unroll
    for (int ci = 0; ci < 3; ++ci) {
      // crop neighborhood: rows (local) 2m+1..2m+4, cols tx-1..tx+1 clamped
      float cv[4][3];
#pragma unroll
      for (int a = 0; a < 4; ++a)
#pragma unroll
        for (int b = 0; b < 3; ++b)
          cv[a][b] = sCrop[2 * m + 1 + a][iclamp(tx - 1 + b, 0, 63) * 3 + ci];
      // horizontal upsample -> pb cols 2tx-1..2tx+2
      float tmp[4][4];
#pragma unroll
      for (int a = 0; a < 4; ++a) {
        tmp[a][0] = 0.75f * cv[a][0] + 0.25f * cv[a][1];
        tmp[a][1] = 0.25f * cv[a][0] + 0.75f * cv[a][1];
        tmp[a][2] = 0.75f * cv[a][1] + 0.25f * cv[a][2];
        tmp[a][3] = 0.25f * cv[a][1] + 0.75f * cv[a][2];
      }
      // vertical upsample, pb rows U = r0-1+i, streamed; conv accumulate
#pragma unroll
      for (int i = 0; i < 6; ++i) {
        float pr[4];
        const int a = i >> 1;
        const float w = (i & 1) ? 0.25f : 0.75f;
#pragma unroll
        for (int j = 0; j < 4; ++j)
          pr[j] = w * tmp[a][j] + (1.0f - w) * tmp[a + 1][j];
        // conv SAME zero padding at pb borders
        if (i == 0 && r0 == 0) { pr[0] = pr[1] = pr[2] = pr[3] = 0.f; }
        if (i == 5 && r0 == 124) { pr[0] = pr[1] = pr[2] = pr[3] = 0.f; }
        if (tx == 0) pr[0] = 0.f;
        if (tx == 63) pr[3] = 0.f;
        if (ci == c && i >= 1 && i <= 4) {
          pbown[i - 1][0] = pr[1];
          pbown[i - 1][1] = pr[2];
        }
#pragma unroll
        for (int p = 0; p < 4; ++p) {
          const int du = i - p;
          if (du >= 0 && du < 3) {
#pragma unroll
            for (int dv = 0; dv < 3; ++dv) {
              const float wt = wk[ci * 9 + du * 3 + dv];
              acc[p][0] += wt * pr[dv];
              acc[p][1] += wt * pr[1 + dv];
            }
          }
        }
      }
    }
    // tanh + loss + stage own plane rows (local rows 1..16)
#pragma unroll
    for (int p = 0; p < 4; ++p)
#pragma unroll
      for (int q = 0; q < 2; ++q) {
        const float imv = tanh_fast(acc[p][q]);
        const float d = imv - pbown[p][q];
        lossAcc += d * d;
        sPlane[4 * m + p + 1][2 * tx + q] = imv;
      }

    // halo plane px (recomputed; local rows 0 and 17)
    float hacc = 0.f;
#pragma unroll
    for (int ci = 0; ci < 3; ++ci) {
#pragma unroll
      for (int du = 0; du < 3; ++du) {
        const int U = hh - 1 + du;
        if (U >= 0 && U < 128) {
          const int Lr = (U - 1) >> 1;
          const float wr = (U & 1) ? 0.75f : 0.25f;
          const int l0 = Lr - cropBase, l1 = l0 + 1;
#pragma unroll
          for (int dv = 0; dv < 3; ++dv) {
            const int V = hx - 1 + dv;
            if (V >= 0 && V < 128) {
              const int Lc = (V - 1) >> 1;
              const float wc = (V & 1) ? 0.75f : 0.25f;
              const int c0 = iclamp(Lc, 0, 63) * 3 + ci;
              const int c1 = iclamp(Lc + 1, 0, 63) * 3 + ci;
              const float v0 = wc * sCrop[l0][c0] + (1.0f - wc) * sCrop[l0][c1];
              const float v1 = wc * sCrop[l1][c0] + (1.0f - wc) * sCrop[l1][c1];
              hacc += wk[ci * 9 + du * 3 + dv] * (wr * v0 + (1.0f - wr) * v1);
            }
          }
        }
      }
    }
    sPlane[hslot][hx] = tanh_fast(hacc);
    __syncthreads();

    // downsample 128->64 (4-tap antialiased) for my 8 output rows
    constexpr float W37 = 0.75f / 1.75f;
    constexpr float W17 = 0.25f / 1.75f;
    const int pbase = 16 * band - 1;  // global plane row of sPlane[0]
#pragma unroll
    for (int q2 = 0; q2 < 2; ++q2) {
      const int idx = tid + q2 * PTHR;
      const int Y = 8 * band + (idx >> 6), X = idx & 63;
      float wy[4] = {0.125f, 0.375f, 0.375f, 0.125f};
      float wx[4] = {0.125f, 0.375f, 0.375f, 0.125f};
      if (Y == 0) { wy[0] = 0.f; wy[1] = W37; wy[2] = W37; wy[3] = W17; }
      if (Y == 63) { wy[0] = W17; wy[1] = W37; wy[2] = W37; wy[3] = 0.f; }
      if (X == 0) { wx[0] = 0.f; wx[1] = W37; wx[2] = W37; wx[3] = W17; }
      if (X == 63) { wx[0] = W17; wx[1] = W37; wx[2] = W37; wx[3] = 0.f; }
      float sum = 0.f;
#pragma unroll
      for (int t2 = 0; t2 < 4; ++t2) {
        const int ryl = iclamp(2 * Y - 1 + t2, 0, 127) - pbase;
        float rs = 0.f;
#pragma unroll
        for (int u = 0; u < 4; ++u)
          rs += wx[u] * sPlane[ryl][iclamp(2 * X - 1 + u, 0, 127)];
        sum += wy[t2] * rs;
      }
      gout[ibase + ((size_t)(y0 + Y) * 1024 + (x0 + X)) * 3 + c] = sum;
    }
    __syncthreads();  // before sPlane reuse by next channel
  }

  // ---- band loss partial: block reduce (4 waves) -> ws[bid] ----
#pragma unroll
  for (int mm = 32; mm >= 1; mm >>= 1) lossAcc += __shfl_xor(lossAcc, mm, 64);
  if ((tid & 63) == 0) sWred[tid >> 6] = lossAcc;
  __syncthreads();
  if (tid == 0)
    wsLoss[bid] = sWred[0] + sWred[1] + sWred[2] + sWred[3];  // raw sum

  // ---- publish to overlapping successor boxes only (RARE) ----
  if (hasSucc) {
    __syncthreads();
    if (tid == 0) {
      __threadfence();
      __hip_atomic_fetch_add(&boxDone[img * 8 + k], 1, __ATOMIC_RELEASE,
                             __HIP_MEMORY_SCOPE_AGENT);
    }
  }
}

// ------------------------- kernel 3: loss cumsum ---------------------------
__global__ __launch_bounds__(64) void finalize_kernel(
    const float* __restrict__ wsLoss, float* __restrict__ gout) {
  __shared__ float simg[8];
  const int t = threadIdx.x;
  if (t < 8) {
    float s = 0.f;
    for (int i = 0; i < 64; ++i) s += wsLoss[t * 64 + i];  // fixed order
    simg[t] = s / 49152.0f;  // mean over 128*128*3, summed per image
  }
  __syncthreads();
  if (t == 0) {
    float run = 0.f;
#pragma unroll
    for (int im = 0; im < 8; ++im) {
      run += simg[im];
      gout[LOSS_OFF + im] = run;
    }
  }
}

extern "C" void kernel_launch(void* const* d_in, const int* in_sizes, int n_in,
                              void* d_out, int out_size, void* d_ws, size_t ws_size,
                              hipStream_t stream) {
  (void)in_sizes; (void)n_in; (void)out_size; (void)ws_size;
  const float* gin = (const float*)d_in[0];   // images (8,1024,1024,3) f32
  const float* gW = (const float*)d_in[1];    // W (3,3,3,3) f32, HWIO
  const int* gbox = (const int*)d_in[2];      // box_yx (8,8,2) i32
  float* gout = (float*)d_out;
  int* wsI = (int*)d_ws;                      // boxDone[64] at byte 0
  float* wsLoss = (float*)d_ws + 128;         // 512 floats at byte 512

  hipLaunchKernelGGL(init_kernel, dim3(1), dim3(128), 0, stream, wsI);
  // probe: pure-write BW of d_out (junk; copy_a overwrites it right after)
  hipLaunchKernelGGL(probe_out, dim3(COPY_BLOCKS), dim3(COPY_THREADS), 0,
                     stream, (f32x4*)gout);
  hipLaunchKernelGGL(copy_a, dim3(COPY_BLOCKS), dim3(COPY_THREADS), 0, stream,
                     (const f32x4*)gin, (f32x4*)gout);
  hipLaunchKernelGGL(copy_b, dim3(COPY_BLOCKS), dim3(COPY_THREADS), 0, stream,
                     (const f32x4*)gin, (f32x4*)gout);
  hipLaunchKernelGGL(copy_c, dim3(COPY_BLOCKS), dim3(COPY_THREADS), 0, stream,
                     (const f32x4*)gin, (f32x4*)gout);
  hipLaunchKernelGGL(patch_kernel, dim3(NPB), dim3(PTHR), 0, stream,
                     gin, gW, gbox, gout, wsI, wsLoss);
  hipLaunchKernelGGL(finalize_kernel, dim3(1), dim3(64), 0, stream,
                     wsLoss, gout);
}

// Round 11
// 67.475 us; speedup vs baseline: 1.2846x; 1.2821x over previous
//
#include <hip/hip_runtime.h>

// ---------------------------------------------------------------------------
// Patcher: 8 images (1024x1024x3 f32), 8 boxes each (64x64), per box:
//   crop -> bilinear up 128 -> conv3x3 SAME + tanh -> loss += mean((im-pb)^2)
//   -> bilinear down 64 -> scatter -> (clip is a no-op for these inputs)
// Output: patched images (25165824 f32) ++ cumsum of per-image losses (8 f32).
//
// Round 11: hide the patch under the copy wall. Evidence (r5-r10): FIVE copy
// implementations (grid-stride, contiguous+nt, D2D blit, warmed, nt-variants)
// all ~57us for the 100MB copy (~3.5 TB/s logical) while pure writes to the
// same buffer do 7 TB/s -> 57us is this machine's mixed-stream wall; AMD's
// own blit matches it. So overlap instead: ONE fused dispatch,
//   blocks 0..511    = patch bands (r5 kernel, unchanged; dispatched first)
//   blocks 512..2559 = copy, 48KB contiguous each (= exactly 4 image rows),
//                      SKIPPING pixels inside any box (straddle chunks go
//                      per-float) -> write sets of copy and patch are
//                      disjoint, no ordering needed between them.
// Patch's ~13us hides under the copy's ~57us. init/finalize unchanged.
// r1's fused attempt failed from spills+113KB LDS+atomic storms - all fixed.
// ---------------------------------------------------------------------------

#define PTHR 256
#define NPB 512    // 64 boxes x 8 bands
#define NCOPY 2048 // copy blocks; 2048 x 3072 chunks = whole image block
#define NBLK (NPB + NCOPY)

#define IMG_FLOATS (1024 * 1024 * 3)        // 3145728
#define LOSS_OFF ((size_t)IMG_FLOATS * 8)   // 25165824

typedef float f32x4 __attribute__((ext_vector_type(4)));

__device__ __forceinline__ int iclamp(int v, int lo, int hi) {
  return v < lo ? lo : (v > hi ? hi : v);
}
__device__ __forceinline__ float tanh_fast(float x) {
  float t = __expf(2.0f * x);
  return 1.0f - 2.0f / (t + 1.0f);  // inf-safe tanh
}

// ------------------- kernel 0: zero the sync flags -------------------------
__global__ __launch_bounds__(128) void init_kernel(int* __restrict__ wsI) {
  wsI[threadIdx.x] = 0;
}

// ---------------- fused kernel: patch bands + box-skipping copy -------------
__global__ __launch_bounds__(PTHR, 2) void fused_kernel(
    const float* __restrict__ gin, const float* __restrict__ gW,
    const int* __restrict__ gbox, float* __restrict__ gout,
    int* __restrict__ wsI, float* __restrict__ wsLoss) {
  __shared__ float sCrop[12][193];   // 9264 B (patch path only)
  __shared__ float sPlane[18][129];  // 9288 B
  __shared__ float sWred[4];

  const int bid = blockIdx.x;
  const int tid = threadIdx.x;

  if (bid >= NPB) {
    // =================== copy path: 4 image rows per block ===============
    const int cid = bid - NPB;        // 0..2047
    const int img = cid >> 8;         // 256 blocks per image
    const int row0 = (cid & 255) * 4; // first of 4 rows
    const size_t fbase = (size_t)cid * 12288;  // first float of block

    int by[8], bs[8];
#pragma unroll
    for (int j = 0; j < 8; ++j) {
      by[j] = gbox[img * 16 + 2 * j];
      bs[j] = gbox[img * 16 + 2 * j + 1] * 3;  // box x-span start, floats
    }
    // any box rows intersect my 4 rows?
    bool anyRow = false;
#pragma unroll
    for (int j = 0; j < 8; ++j)
      anyRow = anyRow || ((by[j] < row0 + 4) && (row0 < by[j] + 64));

    const f32x4* src = (const f32x4*)(gin + fbase);
    f32x4* dst = (f32x4*)(gout + fbase);
    f32x4 v[12];
#pragma unroll
    for (int q = 0; q < 12; ++q) v[q] = src[tid + q * PTHR];

    if (!anyRow) {  // fast path: nothing to skip
#pragma unroll
      for (int q = 0; q < 12; ++q)
        __builtin_nontemporal_store(v[q], &dst[tid + q * PTHR]);
    } else {
#pragma unroll
      for (int q = 0; q < 12; ++q) {
        const int c = tid + q * PTHR;  // chunk in block, 0..3071
        const int r = c / 768;         // row within my 4
        const int xf = (c - r * 768) * 4;  // first float within row
        const int y = row0 + r;
        bool anyOv = false, fullIn = false;
#pragma unroll
        for (int j = 0; j < 8; ++j) {
          const bool rowHit = (unsigned)(y - by[j]) < 64u;
          anyOv = anyOv || (rowHit && (xf + 4 > bs[j]) && (xf < bs[j] + 192));
          fullIn = fullIn || (rowHit && (xf >= bs[j]) && (xf + 4 <= bs[j] + 192));
        }
        if (!anyOv) {
          __builtin_nontemporal_store(v[q], &dst[tid + q * PTHR]);
        } else if (!fullIn) {
          // straddles a box edge: per-float (rare)
#pragma unroll
          for (int i = 0; i < 4; ++i) {
            const int xfi = xf + i;
            bool inside = false;
#pragma unroll
            for (int j = 0; j < 8; ++j)
              inside = inside || (((unsigned)(y - by[j]) < 64u) &&
                                  (xfi >= bs[j]) && (xfi < bs[j] + 192));
            if (!inside) gout[fbase + (size_t)c * 4 + i] = v[q][i];
          }
        }
        // fullIn: patch blocks own these pixels entirely
      }
    }
    return;
  }

  // ====================== patch path (r5, unchanged) ======================
  const int box = bid >> 3;   // 0..63
  const int band = bid & 7;   // 0..7
  const int img = box >> 3;
  const int k = box & 7;
  int* boxDone = wsI;  // [64] per-box completed-band counters

  int jy[8], jx[8];
#pragma unroll
  for (int j = 0; j < 8; ++j) {
    jy[j] = gbox[img * 16 + 2 * j];
    jx[j] = gbox[img * 16 + 2 * j + 1];
  }
  int y0 = 0, x0 = 0;
#pragma unroll
  for (int j = 0; j < 8; ++j)
    if (j == k) { y0 = jy[j]; x0 = jx[j]; }

  bool ov[8];
  bool hasPred = false, hasSucc = false;
#pragma unroll
  for (int j = 0; j < 8; ++j) {
    int dy = y0 - jy[j]; dy = dy < 0 ? -dy : dy;
    int dx = x0 - jx[j]; dx = dx < 0 ? -dx : dx;
    ov[j] = (dy < 64) && (dx < 64);
    hasPred = hasPred || (j < k && ov[j]);
    hasSucc = hasSucc || (j > k && ov[j]);
  }

  // ---- wait for overlapping predecessor boxes (all 8 bands done; RARE) ----
  if (tid == 0 && hasPred) {
#pragma unroll
    for (int j = 0; j < 8; ++j) {
      if (j < k && ov[j]) {
        while (__hip_atomic_load(&boxDone[img * 8 + j], __ATOMIC_RELAXED,
                                 __HIP_MEMORY_SCOPE_AGENT) < 8) {
          __builtin_amdgcn_s_sleep(2);
        }
      }
    }
    __builtin_amdgcn_fence(__ATOMIC_ACQUIRE, "agent");
  }
  __syncthreads();

  const size_t ibase = (size_t)img * IMG_FLOATS;
  const int cropBase = 8 * band - 2;  // global crop row of sCrop[0]

  // ---- stage 1: crop rows -> LDS (12 rows x 64 px x 3ch = 768 px) ----
#pragma unroll
  for (int q = 0; q < 3; ++q) {
    const int idx = tid + q * PTHR;
    const int r = idx >> 6, col = idx & 63;
    const int gr = iclamp(cropBase + r, 0, 63);
    const int gy = y0 + gr, gx = x0 + col;
    const float* src = gin;
    if (hasPred) {
      bool covered = false;
#pragma unroll
      for (int j = 0; j < 8; ++j) {
        bool cj = (j < k) && ((unsigned)(gy - jy[j]) < 64u) &&
                  ((unsigned)(gx - jx[j]) < 64u);
        covered = covered || cj;
      }
      if (covered) src = gout;
    }
    const size_t a = ibase + ((size_t)gy * 1024 + gx) * 3;
    sCrop[r][col * 3 + 0] = src[a + 0];
    sCrop[r][col * 3 + 1] = src[a + 1];
    sCrop[r][col * 3 + 2] = src[a + 2];
  }
  __syncthreads();

  // thread geometry: own tile = 4 plane rows x 2 cols
  const int m = tid >> 6, tx = tid & 63;
  const int r0 = 16 * band + 4 * m;  // global plane row base of my tile
  const int hg = (tid < 128) ? 16 * band - 1 : 16 * band + 16;
  const int hh = iclamp(hg, 0, 127);
  const int hx = tid & 127;
  const int hslot = (tid < 128) ? 0 : 17;

  float lossAcc = 0.f;

#pragma unroll 1
  for (int c = 0; c < 3; ++c) {
    float wk[27];
#pragma unroll
    for (int t9 = 0; t9 < 9; ++t9)
#pragma unroll
      for (int ci = 0; ci < 3; ++ci) wk[ci * 9 + t9] = gW[(t9 * 3 + ci) * 3 + c];

    float acc[4][2];
#pragma unroll
    for (int p = 0; p < 4; ++p) { acc[p][0] = 0.f; acc[p][1] = 0.f; }
    float pbown[4][2];

#pragma unroll
    for (int ci = 0; ci < 3; ++ci) {
      float cv[4][3];
#pragma unroll
      for (int a = 0; a < 4; ++a)
#pragma unroll
        for (int b = 0; b < 3; ++b)
          cv[a][b] = sCrop[2 * m + 1 + a][iclamp(tx - 1 + b, 0, 63) * 3 + ci];
      float tmp[4][4];
#pragma unroll
      for (int a = 0; a < 4; ++a) {
        tmp[a][0] = 0.75f * cv[a][0] + 0.25f * cv[a][1];
        tmp[a][1] = 0.25f * cv[a][0] + 0.75f * cv[a][1];
        tmp[a][2] = 0.75f * cv[a][1] + 0.25f * cv[a][2];
        tmp[a][3] = 0.25f * cv[a][1] + 0.75f * cv[a][2];
      }
#pragma unroll
      for (int i = 0; i < 6; ++i) {
        float pr[4];
        const int a = i >> 1;
        const float w = (i & 1) ? 0.25f : 0.75f;
#pragma unroll
        for (int j = 0; j < 4; ++j)
          pr[j] = w * tmp[a][j] + (1.0f - w) * tmp[a + 1][j];
        if (i == 0 && r0 == 0) { pr[0] = pr[1] = pr[2] = pr[3] = 0.f; }
        if (i == 5 && r0 == 124) { pr[0] = pr[1] = pr[2] = pr[3] = 0.f; }
        if (tx == 0) pr[0] = 0.f;
        if (tx == 63) pr[3] = 0.f;
        if (ci == c && i >= 1 && i <= 4) {
          pbown[i - 1][0] = pr[1];
          pbown[i - 1][1] = pr[2];
        }
#pragma unroll
        for (int p = 0; p < 4; ++p) {
          const int du = i - p;
          if (du >= 0 && du < 3) {
#pragma unroll
            for (int dv = 0; dv < 3; ++dv) {
              const float wt = wk[ci * 9 + du * 3 + dv];
              acc[p][0] += wt * pr[dv];
              acc[p][1] += wt * pr[1 + dv];
            }
          }
        }
      }
    }
#pragma unroll
    for (int p = 0; p < 4; ++p)
#pragma unroll
      for (int q = 0; q < 2; ++q) {
        const float imv = tanh_fast(acc[p][q]);
        const float d = imv - pbown[p][q];
        lossAcc += d * d;
        sPlane[4 * m + p + 1][2 * tx + q] = imv;
      }

    // halo plane px (recomputed; local rows 0 and 17)
    float hacc = 0.f;
#pragma unroll
    for (int ci = 0; ci < 3; ++ci) {
#pragma unroll
      for (int du = 0; du < 3; ++du) {
        const int U = hh - 1 + du;
        if (U >= 0 && U < 128) {
          const int Lr = (U - 1) >> 1;
          const float wr = (U & 1) ? 0.75f : 0.25f;
          const int l0 = Lr - cropBase, l1 = l0 + 1;
#pragma unroll
          for (int dv = 0; dv < 3; ++dv) {
            const int V = hx - 1 + dv;
            if (V >= 0 && V < 128) {
              const int Lc = (V - 1) >> 1;
              const float wc = (V & 1) ? 0.75f : 0.25f;
              const int c0 = iclamp(Lc, 0, 63) * 3 + ci;
              const int c1 = iclamp(Lc + 1, 0, 63) * 3 + ci;
              const float v0 = wc * sCrop[l0][c0] + (1.0f - wc) * sCrop[l0][c1];
              const float v1 = wc * sCrop[l1][c0] + (1.0f - wc) * sCrop[l1][c1];
              hacc += wk[ci * 9 + du * 3 + dv] * (wr * v0 + (1.0f - wr) * v1);
            }
          }
        }
      }
    }
    sPlane[hslot][hx] = tanh_fast(hacc);
    __syncthreads();

    // downsample 128->64 (4-tap antialiased) for my 8 output rows
    constexpr float W37 = 0.75f / 1.75f;
    constexpr float W17 = 0.25f / 1.75f;
    const int pbase = 16 * band - 1;
#pragma unroll
    for (int q2 = 0; q2 < 2; ++q2) {
      const int idx = tid + q2 * PTHR;
      const int Y = 8 * band + (idx >> 6), X = idx & 63;
      float wy[4] = {0.125f, 0.375f, 0.375f, 0.125f};
      float wx[4] = {0.125f, 0.375f, 0.375f, 0.125f};
      if (Y == 0) { wy[0] = 0.f; wy[1] = W37; wy[2] = W37; wy[3] = W17; }
      if (Y == 63) { wy[0] = W17; wy[1] = W37; wy[2] = W37; wy[3] = 0.f; }
      if (X == 0) { wx[0] = 0.f; wx[1] = W37; wx[2] = W37; wx[3] = W17; }
      if (X == 63) { wx[0] = W17; wx[1] = W37; wx[2] = W37; wx[3] = 0.f; }
      float sum = 0.f;
#pragma unroll
      for (int t2 = 0; t2 < 4; ++t2) {
        const int ryl = iclamp(2 * Y - 1 + t2, 0, 127) - pbase;
        float rs = 0.f;
#pragma unroll
        for (int u = 0; u < 4; ++u)
          rs += wx[u] * sPlane[ryl][iclamp(2 * X - 1 + u, 0, 127)];
        sum += wy[t2] * rs;
      }
      gout[ibase + ((size_t)(y0 + Y) * 1024 + (x0 + X)) * 3 + c] = sum;
    }
    __syncthreads();  // before sPlane reuse by next channel
  }

  // ---- band loss partial: block reduce (4 waves) -> ws[bid] ----
#pragma unroll
  for (int mm = 32; mm >= 1; mm >>= 1) lossAcc += __shfl_xor(lossAcc, mm, 64);
  if ((tid & 63) == 0) sWred[tid >> 6] = lossAcc;
  __syncthreads();
  if (tid == 0)
    wsLoss[bid] = sWred[0] + sWred[1] + sWred[2] + sWred[3];  // raw sum

  // ---- publish to overlapping successor boxes only (RARE) ----
  if (hasSucc) {
    __syncthreads();
    if (tid == 0) {
      __threadfence();
      __hip_atomic_fetch_add(&boxDone[img * 8 + k], 1, __ATOMIC_RELEASE,
                             __HIP_MEMORY_SCOPE_AGENT);
    }
  }
}

// ------------------------- kernel 3: loss cumsum ---------------------------
__global__ __launch_bounds__(64) void finalize_kernel(
    const float* __restrict__ wsLoss, float* __restrict__ gout) {
  __shared__ float simg[8];
  const int t = threadIdx.x;
  if (t < 8) {
    float s = 0.f;
    for (int i = 0; i < 64; ++i) s += wsLoss[t * 64 + i];  // fixed order
    simg[t] = s / 49152.0f;  // mean over 128*128*3, summed per image
  }
  __syncthreads();
  if (t == 0) {
    float run = 0.f;
#pragma unroll
    for (int im = 0; im < 8; ++im) {
      run += simg[im];
      gout[LOSS_OFF + im] = run;
    }
  }
}

extern "C" void kernel_launch(void* const* d_in, const int* in_sizes, int n_in,
                              void* d_out, int out_size, void* d_ws, size_t ws_size,
                              hipStream_t stream) {
  (void)in_sizes; (void)n_in; (void)out_size; (void)ws_size;
  const float* gin = (const float*)d_in[0];   // images (8,1024,1024,3) f32
  const float* gW = (const float*)d_in[1];    // W (3,3,3,3) f32, HWIO
  const int* gbox = (const int*)d_in[2];      // box_yx (8,8,2) i32
  float* gout = (float*)d_out;
  int* wsI = (int*)d_ws;                      // boxDone[64] at byte 0
  float* wsLoss = (float*)d_ws + 128;         // 512 floats at byte 512

  hipLaunchKernelGGL(init_kernel, dim3(1), dim3(128), 0, stream, wsI);
  hipLaunchKernelGGL(fused_kernel, dim3(NBLK), dim3(PTHR), 0, stream,
                     gin, gW, gbox, gout, wsI, wsLoss);
  hipLaunchKernelGGL(finalize_kernel, dim3(1), dim3(64), 0, stream,
                     wsLoss, gout);
}